// Round 6
// baseline (935.143 us; speedup 1.0000x reference)
//
#include <hip/hip_runtime.h>
#include <math.h>

#define N_NODES 100000
#define N_EDGES 3200000
#define NCLASS  64
#define TOPK    16
#define NHID    128
#define DEG     6

#define NBUCK   391          // ceil(100000/256) buckets of 256 rows
#define BUCKCAP 9216         // edges per bucket region; mean 8184, ~11 sigma headroom
#define P1_NWG  512          // phase1 blocks (2/CU)
#define P1_CHUNK ((N_EDGES + P1_NWG - 1) / P1_NWG)   // 6250

// ---------- bf16 helpers ----------
__device__ __forceinline__ float bf2f(unsigned short u) {
    return __uint_as_float(((unsigned)u) << 16);
}
__device__ __forceinline__ unsigned short f2bf(float f) {
    unsigned u = __float_as_uint(f);
    u = (u + 0x7FFFu + ((u >> 16) & 1u)) >> 16;   // round-to-nearest-even
    return (unsigned short)u;
}

// ---------- wave helpers (wave64) ----------
__device__ __forceinline__ float wave_max(float v) {
    #pragma unroll
    for (int off = 1; off < 64; off <<= 1) v = fmaxf(v, __shfl_xor(v, off));
    return v;
}
__device__ __forceinline__ float wave_sum(float v) {
    #pragma unroll
    for (int off = 1; off < 64; off <<= 1) v += __shfl_xor(v, off);
    return v;
}

// ---------- CSR build, phase 1: LDS-buffered multi-split ----------
// Bulk stores to staging are full 64B lines (8 edges x 8B, 8 lanes, aligned):
// the fix for the 41 B/edge partial-line write amplification seen in r1-r5.
__global__ __launch_bounds__(256) void phase1_bucket(
        const int* __restrict__ erow, const int* __restrict__ ecol,
        const float* __restrict__ eval, int* __restrict__ fill,
        int2* __restrict__ staging) {
    __shared__ int2 buf[NBUCK][8];
    __shared__ int  lcnt[NBUCK];
    int tid = threadIdx.x;
    int wv = tid >> 6, lane = tid & 63;
    for (int b = tid; b < NBUCK; b += 256) lcnt[b] = 0;
    __syncthreads();

    int base  = blockIdx.x * P1_CHUNK;
    int limit = min(base + P1_CHUNK, N_EDGES);
    int i = base + tid;
    bool have = false;
    int2 ed = make_int2(0, 0);
    int  eb = 0;

    while (true) {
        // acquire a new edge if not holding one
        if (!have && i < limit) {
            int   r = __builtin_nontemporal_load(&erow[i]);
            int   c = __builtin_nontemporal_load(&ecol[i]);
            float w = __builtin_nontemporal_load(&eval[i]);
            ed.x = (c << 8) | (r & 255);   // col:17b << 8 | row_local:8b
            ed.y = __float_as_int(w);
            eb = r >> 8;
            i += 256;
            have = true;
        }
        // try to insert into the bucket's LDS buffer
        if (have) {
            int p = atomicAdd(&lcnt[eb], 1);
            if (p < 8) { buf[eb][p] = ed; have = false; }
            // p >= 8: buffer full this round; hold and retry after flush
        }
        int pending = __syncthreads_count((int)(have || (i < limit)));
        // flush full buckets; wave wv owns buckets b with b%4==wv
        for (int b = wv; b < NBUCK; b += 4) {
            if (lcnt[b] >= 8) {
                int pos = 0;
                if (lane == 0) pos = atomicAdd(&fill[b * 16], 8);
                pos = __shfl(pos, 0);
                if (lane < 8)
                    staging[(size_t)b * BUCKCAP + pos + lane] = buf[b][lane];
                if (lane == 0) lcnt[b] = 0;
            }
        }
        __syncthreads();
        if (pending == 0) break;
    }
    // residual flush (0..7 entries per bucket)
    for (int b = wv; b < NBUCK; b += 4) {
        int c = lcnt[b];
        if (c > 0) {
            int pos = 0;
            if (lane == 0) pos = atomicAdd(&fill[b * 16], c);
            pos = __shfl(pos, 0);
            if (lane < c)
                staging[(size_t)b * BUCKCAP + pos + lane] = buf[b][lane];
        }
    }
}

// ---------- CSR build: prefix over bucket totals ----------
__global__ void bucket_scan(const int* __restrict__ fill, int* __restrict__ bucket_base,
                            int* __restrict__ row_ptr) {
    __shared__ int sdat[512];
    int tid = threadIdx.x;
    int c = 0;
    if (tid < NBUCK) c = min(fill[tid * 16], BUCKCAP);
    sdat[tid] = c;
    __syncthreads();
    for (int off = 1; off < 512; off <<= 1) {
        int t = (tid >= off) ? sdat[tid - off] : 0;
        __syncthreads();
        sdat[tid] += t;
        __syncthreads();
    }
    if (tid < NBUCK) bucket_base[tid] = sdat[tid] - c;   // exclusive
    if (tid == 0) row_ptr[N_NODES] = sdat[511];          // == N_EDGES
}

// ---------- CSR build, phase 2: per-bucket compaction + row_ptr ----------
__global__ __launch_bounds__(256) void phase2_build(
        const int2* __restrict__ staging, const int* __restrict__ fill,
        const int* __restrict__ bucket_base, int* __restrict__ row_ptr,
        int2* __restrict__ edges_s) {
    __shared__ int lhist[256];
    __shared__ int lscan[256];
    __shared__ int lfill[256];
    int b = blockIdx.x, tid = threadIdx.x;
    int c = min(fill[b * 16], BUCKCAP);
    const int2* seg = staging + (size_t)b * BUCKCAP;
    lhist[tid] = 0;
    __syncthreads();
    for (int j = tid; j < c; j += 256) atomicAdd(&lhist[seg[j].x & 255], 1);
    __syncthreads();
    int v = lhist[tid];
    lscan[tid] = v;
    __syncthreads();
    for (int off = 1; off < 256; off <<= 1) {
        int t = (tid >= off) ? lscan[tid - off] : 0;
        __syncthreads();
        lscan[tid] += t;
        __syncthreads();
    }
    int excl = bucket_base[b] + (lscan[tid] - v);
    int grow = b * 256 + tid;
    if (grow < N_NODES) row_ptr[grow] = excl;
    lfill[tid] = excl;
    __syncthreads();
    for (int j = tid; j < c; j += 256) {
        int2 e = seg[j];
        int rl = e.x & 255;
        int pos = atomicAdd(&lfill[rl], 1);
        edges_s[pos] = make_int2((int)(((unsigned)e.x) >> 8), e.y);
    }
}

// ---------- gating: bitonic sort64 -> top16 softmax -> MLP -> softmax6 ----------
#define GNODES 32   // nodes per block (4 waves x 8 iterations)
__global__ __launch_bounds__(256) void gating_kernel(
        const float* __restrict__ x,  const float* __restrict__ W1,
        const float* __restrict__ b1, const float* __restrict__ W2,
        const float* __restrict__ b2, float* __restrict__ weight,
        float* __restrict__ out_acc, unsigned short* __restrict__ xbf) {
    __shared__ float sW1t[TOPK * NHID];   // transposed: [k][j]
    __shared__ float sb1[NHID];
    __shared__ float sW2[DEG * NHID];
    __shared__ float sb2[DEG];
    int tid = threadIdx.x;
    for (int idx = tid; idx < NHID * TOPK; idx += 256) {
        int k = idx / NHID, j = idx - k * NHID;
        sW1t[idx] = W1[j * TOPK + k];
    }
    for (int i = tid; i < NHID; i += 256) sb1[i] = b1[i];
    for (int i = tid; i < DEG * NHID; i += 256) sW2[i] = W2[i];
    if (tid < DEG) sb2[tid] = b2[tid];
    __syncthreads();

    int wave = tid >> 6;
    int lane = tid & 63;

    for (int it = 0; it < GNODES / 4; it++) {
        int node = blockIdx.x * GNODES + it * 4 + wave;
        if (node >= N_NODES) continue;

        float xv = x[node * NCLASS + lane];
        xbf[node * NCLASS + lane] = f2bf(xv);

        // full ascending bitonic sort of x across the wave (21 steps)
        float v = xv;
        #pragma unroll
        for (int k = 2; k <= 64; k <<= 1) {
            #pragma unroll
            for (int j = k >> 1; j > 0; j >>= 1) {
                float o = __shfl_xor(v, j);
                bool keep_small = (((lane & j) == 0) == ((lane & k) == 0));
                v = keep_small ? fminf(v, o) : fmaxf(v, o);
            }
        }
        float m = __shfl(v, 63);                 // global max
        float e = __expf(v - m);
        float s = wave_sum(e);                   // softmax denominator
        float inv_s = 1.0f / s;

        float h0 = sb1[lane], h1 = sb1[lane + 64];
        #pragma unroll
        for (int k = 0; k < TOPK; k++) {
            float sv = __shfl(v, 63 - k);        // k-th largest logit
            float tk = __expf(sv - m) * inv_s;   // k-th largest prob
            h0 += tk * sW1t[k * NHID + lane];
            h1 += tk * sW1t[k * NHID + lane + 64];
        }
        h0 = (h0 > 0.f) ? h0 : 0.1f * h0;
        h1 = (h1 > 0.f) ? h1 : 0.1f * h1;

        float w[DEG];
        float wm = -1e30f;
        #pragma unroll
        for (int d = 0; d < DEG; d++) {
            float part = h0 * sW2[d * NHID + lane] + h1 * sW2[d * NHID + lane + 64];
            w[d] = wave_sum(part) + sb2[d];
            wm = fmaxf(wm, w[d]);
        }
        float wsum = 0.f;
        #pragma unroll
        for (int d = 0; d < DEG; d++) { w[d] = __expf(w[d] - wm); wsum += w[d]; }
        float inv = 1.0f / wsum;

        if (lane < DEG) weight[node * DEG + lane] = w[lane] * inv;
        out_acc[node * NCLASS + lane] = w[0] * inv * xv;
    }
}

// ---------- SPMM: 4-edge gather group, scalar (SGPR) edge stream ----------
__device__ __forceinline__ void gather4(const unsigned short* __restrict__ src,
                                        const long long* __restrict__ edq,
                                        int e, int lane, float& acc) {
    long long q0 = __builtin_nontemporal_load(&edq[e]);
    long long q1 = __builtin_nontemporal_load(&edq[e + 1]);
    long long q2 = __builtin_nontemporal_load(&edq[e + 2]);
    long long q3 = __builtin_nontemporal_load(&edq[e + 3]);
    int c0 = __builtin_amdgcn_readfirstlane((int)(unsigned)q0);
    int c1 = __builtin_amdgcn_readfirstlane((int)(unsigned)q1);
    int c2 = __builtin_amdgcn_readfirstlane((int)(unsigned)q2);
    int c3 = __builtin_amdgcn_readfirstlane((int)(unsigned)q3);
    float v0 = __int_as_float(__builtin_amdgcn_readfirstlane((int)(q0 >> 32)));
    float v1 = __int_as_float(__builtin_amdgcn_readfirstlane((int)(q1 >> 32)));
    float v2 = __int_as_float(__builtin_amdgcn_readfirstlane((int)(q2 >> 32)));
    float v3 = __int_as_float(__builtin_amdgcn_readfirstlane((int)(q3 >> 32)));
    float f0 = bf2f(src[c0 * NCLASS + lane]);
    float f1 = bf2f(src[c1 * NCLASS + lane]);
    float f2 = bf2f(src[c2 * NCLASS + lane]);
    float f3 = bf2f(src[c3 * NCLASS + lane]);
    acc += v0 * f0; acc += v1 * f1; acc += v2 * f2; acc += v3 * f3;
}

__device__ __forceinline__ float drain_row(const unsigned short* __restrict__ src,
                                           const long long* __restrict__ edq,
                                           int e, int end, int lane, float acc) {
    for (; e + 4 <= end; e += 4) gather4(src, edq, e, lane, acc);
    for (; e < end; e++) {
        long long q0 = __builtin_nontemporal_load(&edq[e]);
        int   c0 = __builtin_amdgcn_readfirstlane((int)(unsigned)q0);
        float v0 = __int_as_float(__builtin_amdgcn_readfirstlane((int)(q0 >> 32)));
        acc += v0 * bf2f(src[c0 * NCLASS + lane]);
    }
    return acc;
}

// ---------- SPMM hop: wave per ROW-PAIR (2 independent gather chains) ----------
__global__ __launch_bounds__(256) void spmm_kernel(
        const unsigned short* __restrict__ src, unsigned short* __restrict__ dst,
        const int* __restrict__ row_ptr, const int2* __restrict__ edges_s,
        const float* __restrict__ weight,
        float* __restrict__ out_acc, float* __restrict__ final_out,
        int hop, int is_last) {
    int wave = threadIdx.x >> 6;
    int lane = threadIdx.x & 63;
    int wid = blockIdx.x * 4 + wave;          // pair id
    int rA = wid * 2;
    if (rA >= N_NODES) return;
    int rB = rA + 1;                           // N_NODES even -> always valid

    int sA   = __builtin_amdgcn_readfirstlane(row_ptr[rA]);
    int endA = __builtin_amdgcn_readfirstlane(row_ptr[rA + 1]);
    int endB = __builtin_amdgcn_readfirstlane(row_ptr[rA + 2]);

    const long long* edq = (const long long*)edges_s;
    float accA = 0.f, accB = 0.f;
    int eA = sA, eB = endA;
    // interleaved: 8 independent gathers in flight from 2 chains
    while (eA + 4 <= endA && eB + 4 <= endB) {
        gather4(src, edq, eA, lane, accA);
        gather4(src, edq, eB, lane, accB);
        eA += 4; eB += 4;
    }
    accA = drain_row(src, edq, eA, endA, lane, accA);
    accB = drain_row(src, edq, eB, endB, lane, accB);

    float wA = weight[rA * DEG + hop];
    float wB = weight[rB * DEG + hop];
    if (!is_last) {
        dst[rA * NCLASS + lane] = f2bf(accA);
        dst[rB * NCLASS + lane] = f2bf(accB);
        out_acc[rA * NCLASS + lane] += wA * accA;
        out_acc[rB * NCLASS + lane] += wB * accB;
    } else {
        float vA = out_acc[rA * NCLASS + lane] + wA * accA;
        float mA = wave_max(vA);
        float eA2 = __expf(vA - mA);
        float sA2 = wave_sum(eA2);
        final_out[rA * NCLASS + lane] = vA - mA - __logf(sA2);

        float vB = out_acc[rB * NCLASS + lane] + wB * accB;
        float mB = wave_max(vB);
        float eB2 = __expf(vB - mB);
        float sB2 = wave_sum(eB2);
        final_out[rB * NCLASS + lane] = vB - mB - __logf(sB2);
    }
}

extern "C" void kernel_launch(void* const* d_in, const int* in_sizes, int n_in,
                              void* d_out, int out_size, void* d_ws, size_t ws_size,
                              hipStream_t stream) {
    const float* x    = (const float*)d_in[0];
    const int*   erow = (const int*)  d_in[1];
    const int*   ecol = (const int*)  d_in[2];
    const float* eval = (const float*)d_in[3];
    const float* W1   = (const float*)d_in[4];
    const float* b1   = (const float*)d_in[5];
    const float* W2   = (const float*)d_in[6];
    const float* b2   = (const float*)d_in[7];
    float* out = (float*)d_out;   // also the hop-accumulation buffer

    char* ws = (char*)d_ws;
    size_t off = 0;
    auto alloc = [&](size_t bytes) -> void* {
        void* p = ws + off;
        off = (off + bytes + 255) & ~(size_t)255;
        return p;
    };
    // Region A: staging (28.8 MB) is dead before gating runs; xbf/cur0/cur1
    // (38.4 MB) reuse the same space. Stream ordering guarantees safety.
    char* regionA = (char*)alloc((size_t)N_NODES * NCLASS * 2 * 3);   // 38.4 MB
    int2* staging = (int2*)regionA;
    unsigned short* xbf  = (unsigned short*)regionA;
    unsigned short* cur0 = (unsigned short*)(regionA + (size_t)N_NODES * NCLASS * 2);
    unsigned short* cur1 = (unsigned short*)(regionA + (size_t)N_NODES * NCLASS * 4);

    int2*  edges_s     = (int2*)alloc((size_t)N_EDGES * 8);
    int*   row_ptr     = (int*) alloc((size_t)(N_NODES + 1) * 4);
    int*   fill        = (int*) alloc((size_t)NBUCK * 16 * 4);   // 64B-padded counters
    int*   bucket_base = (int*) alloc((size_t)NBUCK * 4);
    float* weight      = (float*)alloc((size_t)N_NODES * DEG * 4);

    const int WB = ((N_NODES / 2) + 3) / 4;          // 12500 (4 row-pairs/block)
    const int GB = (N_NODES + GNODES - 1) / GNODES;  // 3125

    // CSR build: LDS multi-split scatter -> bucket prefix -> compaction
    hipMemsetAsync(fill, 0, (size_t)NBUCK * 16 * 4, stream);
    phase1_bucket<<<P1_NWG, 256, 0, stream>>>(erow, ecol, eval, fill, staging);
    bucket_scan<<<1, 512, 0, stream>>>(fill, bucket_base, row_ptr);
    phase2_build<<<NBUCK, 256, 0, stream>>>(staging, fill, bucket_base, row_ptr, edges_s);

    // gating: weights + out = w0 * x, and bf16 copy of x (overwrites staging)
    gating_kernel<<<GB, 256, 0, stream>>>(x, W1, b1, W2, b2, weight, out, xbf);

    // 5 hops, out accumulated in d_out; last hop fuses log_softmax
    spmm_kernel<<<WB, 256, 0, stream>>>(xbf,  cur0, row_ptr, edges_s, weight, out, out, 1, 0);
    spmm_kernel<<<WB, 256, 0, stream>>>(cur0, cur1, row_ptr, edges_s, weight, out, out, 2, 0);
    spmm_kernel<<<WB, 256, 0, stream>>>(cur1, cur0, row_ptr, edges_s, weight, out, out, 3, 0);
    spmm_kernel<<<WB, 256, 0, stream>>>(cur0, cur1, row_ptr, edges_s, weight, out, out, 4, 0);
    spmm_kernel<<<WB, 256, 0, stream>>>(cur1, cur0, row_ptr, edges_s, weight, out, out, 5, 1);
}